// Round 7
// baseline (176.511 us; speedup 1.0000x reference)
//
#include <hip/hip_runtime.h>

// Problem constants
constexpr int cN1 = 85,  cF1 = 256, cO1 = 200, cE1 = 1360;
constexpr int cN2 = 5625, cF2 = 128, cE2 = 180000;

// Workspace layout (4-byte words), fixed (no padding — atomic targets stay
// small and L2-resident; R6 showed 256B-padding them costs ~16 us):
constexpr int OFF_G2   = 0;              // 11250 f32 (graph2 agg; f32 atomics) [zeroed in K_A]
constexpr int OFF_DEG2 = 11250;          // 5625  i32 (plain-stored by hist role)
constexpr int OFF_G1   = 16876;          // 17000 f32 (graph1 agg; plain stores)
constexpr int OFF_H1   = 33876;          // 17000 f32 (x1 @ W1)
constexpr int OFF_H2   = 50876;          // 11250 f32 (x2 @ W2); even -> float2 ok

// ---------------- K_A: GEMMs + deg2 LDS-histogram + zero g2 (role-split) --------
// roles by blockIdx: [0,8) hist | [8,93) GEMM1 | [93,797) GEMM2 | [797,808) zero
constexpr int HIST_B  = 8;                      // 8 blocks x 704 nodes each
constexpr int NPB     = 704;                    // nodes per hist block (8*704 >= 5625)
constexpr int G1_B    = cN1;                    // 85
constexpr int G2_B    = (cN2 + 7) / 8;          // 704 (8 rows / block)
constexpr int ZERO_B  = 11;                     // 11250 words / (11*256) ~ 4 per thread
constexpr int KA_GRID = HIST_B + G1_B + G2_B + ZERO_B;

__global__ __launch_bounds__(256) void kA_gemm_hist_zero(
    const float* __restrict__ x1, const float* __restrict__ x2,
    const float* __restrict__ W1, const float* __restrict__ W2,
    const int* __restrict__ ei2, float* __restrict__ ws_f)
{
    int* ws_i = reinterpret_cast<int*>(ws_f);
    int b = blockIdx.x, t = threadIdx.x;

    if (b < HIST_B) {
        // deg2 for nodes [lo, hi): scan all 180K dst, bin the ones we own.
        __shared__ int s_h[NPB];
        int lo = b * NPB, hi = min(lo + NPB, cN2), cnt = hi - lo;
        for (int i = t; i < cnt; i += 256) s_h[i] = 0;
        __syncthreads();
        const int* dstp = ei2 + cE2;
        for (int i = t; i < cE2; i += 256) {
            int d = dstp[i];                       // coalesced; L2-resident re-read
            if (d >= lo && d < hi) atomicAdd(&s_h[d - lo], 1);
        }
        __syncthreads();
        for (int i = t; i < cnt; i += 256) ws_i[OFF_DEG2 + lo + i] = s_h[i];
        return;
    }
    b -= HIST_B;

    if (b < G1_B) {
        // GEMM1: h1[b][t] = sum_k x1[b][k] * W1[k][t]  (t < 200)
        if (t < cO1) {
            const float* xr = x1 + b * cF1;        // uniform across block
            float s = 0.f;
            #pragma unroll 8
            for (int k = 0; k < cF1; ++k)
                s = fmaf(xr[k], W1[k * cO1 + t], s);   // coalesced across t
            ws_f[OFF_H1 + b * cO1 + t] = s;
        }
        return;
    }
    b -= G1_B;

    if (b < G2_B) {
        // GEMM2: 32-lane group per row; W2 (1 KB) cache-resident.
        int row = b * 8 + (t >> 5), l = t & 31;
        if (row < cN2) {
            float4 xv = reinterpret_cast<const float4*>(x2 + row * cF2)[l];
            int kb = l * 4;
            float p0 = xv.x * W2[(kb + 0) * 2 + 0] + xv.y * W2[(kb + 1) * 2 + 0]
                     + xv.z * W2[(kb + 2) * 2 + 0] + xv.w * W2[(kb + 3) * 2 + 0];
            float p1 = xv.x * W2[(kb + 0) * 2 + 1] + xv.y * W2[(kb + 1) * 2 + 1]
                     + xv.z * W2[(kb + 2) * 2 + 1] + xv.w * W2[(kb + 3) * 2 + 1];
            #pragma unroll
            for (int m = 16; m >= 1; m >>= 1) {
                p0 += __shfl_xor(p0, m);
                p1 += __shfl_xor(p1, m);
            }
            if (l == 0) {
                ws_f[OFF_H2 + row * 2 + 0] = p0;
                ws_f[OFF_H2 + row * 2 + 1] = p1;
            }
        }
        return;
    }
    b -= G2_B;

    // zero role: g2 accumulator only (45 KB)
    for (int i = b * 256 + t; i < cN2 * 2; i += ZERO_B * 256) ws_f[OFF_G2 + i] = 0.f;
}

// ---------------- K_B: graph1 gather-agg + graph2 scatter (unpadded atomics) ----
// roles: [0,85) g1 aggregation (one block per node) | [85, 85+726) scatter2
constexpr int SC_B    = (cE2 + cN2 + 255) / 256;   // 726
constexpr int KB_GRID = cN1 + SC_B;

__global__ __launch_bounds__(256) void kB_agg(
    const int* __restrict__ ei1, const int* __restrict__ ei2,
    float* __restrict__ ws_f)
{
    const int* ws_i = reinterpret_cast<const int*>(ws_f);
    int b = blockIdx.x, t = threadIdx.x;

    if (b < cN1) {
        // graph1: self-contained gather (deg1 rebuilt in LDS; no global atomics)
        __shared__ int   s_src[cE1];
        __shared__ int   s_dst[cE1];
        __shared__ int   s_deg[cN1];
        __shared__ float s_acc[cO1];
        for (int i = t; i < cE1; i += 256) { s_src[i] = ei1[i]; s_dst[i] = ei1[cE1 + i]; }
        if (t < cN1) s_deg[t] = 0;
        for (int i = t; i < cO1; i += 256) s_acc[i] = 0.f;
        __syncthreads();
        for (int i = t; i < cE1; i += 256) atomicAdd(&s_deg[s_dst[i]], 1);
        __syncthreads();
        int w = t >> 6, lane = t & 63;
        int e0 = w * (cE1 / 4), e1 = e0 + (cE1 / 4);       // 340 edges / wave
        for (int e = e0; e < e1; ++e) {
            if (s_dst[e] == b) {
                int src = s_src[e];
                float dsv = rsqrtf((float)(s_deg[src] + 1));
                const float* hrow = ws_f + OFF_H1 + src * cO1;
                for (int f = lane; f < cO1; f += 64)
                    atomicAdd(&s_acc[f], hrow[f] * dsv);   // LDS atomic, sparse
            }
        }
        __syncthreads();
        float dn = rsqrtf((float)(s_deg[b] + 1));
        for (int i = t; i < cO1; i += 256)
            ws_f[OFF_G1 + b * cO1 + i] =
                dn * (s_acc[i] + dn * ws_f[OFF_H1 + b * cO1 + i]);
        return;
    }
    b -= cN1;

    // graph2 scatter: one thread per edge-unit (real edges + self loops)
    int e = b * 256 + t;
    if (e < cE2 + cN2) {
        int src, dst;
        if (e < cE2) { src = ei2[e]; dst = ei2[cE2 + e]; }
        else         { src = dst = e - cE2; }                    // self loop
        float norm = rsqrtf((float)(ws_i[OFF_DEG2 + src] + 1))
                   * rsqrtf((float)(ws_i[OFF_DEG2 + dst] + 1));
        float2 h = reinterpret_cast<const float2*>(ws_f + OFF_H2)[src];
        atomicAdd(&ws_f[OFF_G2 + dst * 2 + 0], h.x * norm);
        atomicAdd(&ws_f[OFF_G2 + dst * 2 + 1], h.y * norm);
    }
}

// ---------------- K_C: bias + reshape/concat + relu + final linear --------------
__global__ __launch_bounds__(128) void kC_head(
    const float* __restrict__ ws_f,
    const float* __restrict__ b1, const float* __restrict__ b2,
    const float* __restrict__ Wf, const float* __restrict__ bf,
    float* __restrict__ out)
{
    __shared__ float sh[113];
    int r = blockIdx.x, t = threadIdx.x;
    if (t < 113) {
        float v;
        if (t < 68) {
            int f = r * 68 + t;                       // h1.reshape(250,68) flat
            v = ws_f[OFF_G1 + f] + b1[f % 200];
        } else {
            int f = r * 45 + (t - 68);                // h2.reshape(250,45) flat
            v = ws_f[OFF_G2 + f] + b2[f & 1];
        }
        sh[t] = fmaxf(v, 0.f);
    }
    __syncthreads();
    if (t < 5) {
        float s = bf[t];
        #pragma unroll 1
        for (int k = 0; k < 113; ++k)
            s = fmaf(sh[k], Wf[k * 5 + t], s);
        out[r * 5 + t] = s;
    }
}

extern "C" void kernel_launch(void* const* d_in, const int* in_sizes, int n_in,
                              void* d_out, int out_size, void* d_ws, size_t ws_size,
                              hipStream_t stream)
{
    const float* x1 = (const float*)d_in[0];
    const float* x2 = (const float*)d_in[1];
    const float* W1 = (const float*)d_in[2];
    const float* b1 = (const float*)d_in[3];
    const float* W2 = (const float*)d_in[4];
    const float* b2 = (const float*)d_in[5];
    const float* Wf = (const float*)d_in[6];
    const float* bf = (const float*)d_in[7];
    const int*   ei1 = (const int*)d_in[8];
    const int*   ei2 = (const int*)d_in[9];
    float* ws_f = (float*)d_ws;
    float* out  = (float*)d_out;

    kA_gemm_hist_zero<<<KA_GRID, 256, 0, stream>>>(x1, x2, W1, W2, ei2, ws_f);
    kB_agg<<<KB_GRID, 256, 0, stream>>>(ei1, ei2, ws_f);
    kC_head<<<250, 128, 0, stream>>>(ws_f, b1, b2, Wf, bf, out);
}

// Round 8
// 80.616 us; speedup vs baseline: 2.1895x; 2.1895x over previous
//
#include <hip/hip_runtime.h>

// Problem constants
constexpr int cN1 = 85,  cF1 = 256, cO1 = 200, cE1 = 1360;
constexpr int cN2 = 5625, cF2 = 128, cE2 = 180000;

// deg2 is computed as NPART edge-sliced partial histograms (no zero, no atomics):
constexpr int NPART = 8;                 // partial histograms (edge slices)
constexpr int PBINS = 5632;              // bins per partial (>= cN2, 64-aligned)
constexpr int EPP   = cE2 / NPART;       // 22500 edges per hist block

// Workspace layout (4-byte words):
constexpr int OFF_G2   = 0;                          // 11250 f32 [zeroed by K1 role]
constexpr int OFF_PART = 11264;                      // NPART*PBINS i32 (plain-stored)
constexpr int OFF_G1   = OFF_PART + NPART * PBINS;   // 56320: 17000 f32
constexpr int OFF_H1   = OFF_G1 + cN1 * cO1;         // 73320: 17000 f32 (x1@W1)
constexpr int OFF_H2   = OFF_H1 + cN1 * cO1;         // 90320: 11250 f32 (x2@W2), even

// ---------------- K1: partial hists + GEMMs + zero-g2 (role-split grid) ---------
// roles: [0,8) hist | [8,93) GEMM1 | [93,797) GEMM2 | [797,808) zero g2
constexpr int G1_B    = cN1;                  // 85
constexpr int G2_B    = (cN2 + 7) / 8;        // 704
constexpr int ZERO_B  = 11;
constexpr int K1_GRID = NPART + G1_B + G2_B + ZERO_B;   // 808

__global__ __launch_bounds__(256) void k1_hist_gemm_zero(
    const float* __restrict__ x1, const float* __restrict__ x2,
    const float* __restrict__ W1, const float* __restrict__ W2,
    const int* __restrict__ ei2, float* __restrict__ ws_f)
{
    int* ws_i = reinterpret_cast<int*>(ws_f);
    int b = blockIdx.x, t = threadIdx.x;

    if (b < NPART) {
        // Partial histogram: this block scans edges [b*EPP, (b+1)*EPP) only.
        __shared__ int s_h[PBINS];
        for (int i = t; i < PBINS; i += 256) s_h[i] = 0;
        __syncthreads();
        const int* dstp = ei2 + cE2 + b * EPP;
        for (int i = t; i < EPP; i += 256)
            atomicAdd(&s_h[dstp[i]], 1);              // LDS atomic, random bins
        __syncthreads();
        for (int i = t; i < PBINS; i += 256)
            ws_i[OFF_PART + b * PBINS + i] = s_h[i];  // plain store
        return;
    }
    b -= NPART;

    if (b < G1_B) {
        // GEMM1: h1[b][t] = sum_k x1[b][k] * W1[k][t]  (t < 200)
        if (t < cO1) {
            const float* xr = x1 + b * cF1;           // uniform across block
            float s = 0.f;
            #pragma unroll 8
            for (int k = 0; k < cF1; ++k)
                s = fmaf(xr[k], W1[k * cO1 + t], s);  // coalesced across t
            ws_f[OFF_H1 + b * cO1 + t] = s;
        }
        return;
    }
    b -= G1_B;

    if (b < G2_B) {
        // GEMM2: 32-lane group per row; W2 (1 KB) cache-resident.
        int row = b * 8 + (t >> 5), l = t & 31;
        if (row < cN2) {
            float4 xv = reinterpret_cast<const float4*>(x2 + row * cF2)[l];
            int kb = l * 4;
            float p0 = xv.x * W2[(kb + 0) * 2 + 0] + xv.y * W2[(kb + 1) * 2 + 0]
                     + xv.z * W2[(kb + 2) * 2 + 0] + xv.w * W2[(kb + 3) * 2 + 0];
            float p1 = xv.x * W2[(kb + 0) * 2 + 1] + xv.y * W2[(kb + 1) * 2 + 1]
                     + xv.z * W2[(kb + 2) * 2 + 1] + xv.w * W2[(kb + 3) * 2 + 1];
            #pragma unroll
            for (int m = 16; m >= 1; m >>= 1) {
                p0 += __shfl_xor(p0, m);
                p1 += __shfl_xor(p1, m);
            }
            if (l == 0) {
                ws_f[OFF_H2 + row * 2 + 0] = p0;
                ws_f[OFF_H2 + row * 2 + 1] = p1;
            }
        }
        return;
    }
    b -= G2_B;

    // zero role: g2 accumulator (45 KB), disjoint from every K1 write
    for (int i = b * 256 + t; i < cN2 * 2; i += ZERO_B * 256) ws_f[OFF_G2 + i] = 0.f;
}

// ---------------- K2: graph1 gather-agg + graph2 scatter (unpadded atomics) -----
// roles: [0,85) g1 aggregation | [85, 85+726) scatter2
constexpr int SC_B    = (cE2 + cN2 + 255) / 256;   // 726
constexpr int K2_GRID = cN1 + SC_B;

__device__ __forceinline__ int deg2_of(const int* ws_i, int n)
{
    int d = 0;
    #pragma unroll
    for (int p = 0; p < NPART; ++p) d += ws_i[OFF_PART + p * PBINS + n];
    return d;
}

__global__ __launch_bounds__(256) void k2_agg(
    const int* __restrict__ ei1, const int* __restrict__ ei2,
    float* __restrict__ ws_f)
{
    const int* ws_i = reinterpret_cast<const int*>(ws_f);
    int b = blockIdx.x, t = threadIdx.x;

    if (b < cN1) {
        // graph1: self-contained gather (deg1 rebuilt in LDS; no global atomics)
        __shared__ int   s_src[cE1];
        __shared__ int   s_dst[cE1];
        __shared__ int   s_deg[cN1];
        __shared__ float s_acc[cO1];
        for (int i = t; i < cE1; i += 256) { s_src[i] = ei1[i]; s_dst[i] = ei1[cE1 + i]; }
        if (t < cN1) s_deg[t] = 0;
        for (int i = t; i < cO1; i += 256) s_acc[i] = 0.f;
        __syncthreads();
        for (int i = t; i < cE1; i += 256) atomicAdd(&s_deg[s_dst[i]], 1);
        __syncthreads();
        int w = t >> 6, lane = t & 63;
        int e0 = w * (cE1 / 4), e1 = e0 + (cE1 / 4);       // 340 edges / wave
        for (int e = e0; e < e1; ++e) {
            if (s_dst[e] == b) {
                int src = s_src[e];
                float dsv = rsqrtf((float)(s_deg[src] + 1));
                const float* hrow = ws_f + OFF_H1 + src * cO1;
                for (int f = lane; f < cO1; f += 64)
                    atomicAdd(&s_acc[f], hrow[f] * dsv);   // LDS atomic, sparse
            }
        }
        __syncthreads();
        float dn = rsqrtf((float)(s_deg[b] + 1));
        for (int i = t; i < cO1; i += 256)
            ws_f[OFF_G1 + b * cO1 + i] =
                dn * (s_acc[i] + dn * ws_f[OFF_H1 + b * cO1 + i]);
        return;
    }
    b -= cN1;

    // graph2 scatter: one thread per edge-unit (real edges + self loops)
    int e = b * 256 + t;
    if (e < cE2 + cN2) {
        int src, dst;
        if (e < cE2) { src = ei2[e]; dst = ei2[cE2 + e]; }
        else         { src = dst = e - cE2; }                    // self loop
        float norm = rsqrtf((float)(deg2_of(ws_i, src) + 1))
                   * rsqrtf((float)(deg2_of(ws_i, dst) + 1));
        float2 h = reinterpret_cast<const float2*>(ws_f + OFF_H2)[src];
        atomicAdd(&ws_f[OFF_G2 + dst * 2 + 0], h.x * norm);
        atomicAdd(&ws_f[OFF_G2 + dst * 2 + 1], h.y * norm);
    }
}

// ---------------- K3: bias + reshape/concat + relu + final linear ---------------
__global__ __launch_bounds__(128) void k3_head(
    const float* __restrict__ ws_f,
    const float* __restrict__ b1, const float* __restrict__ b2,
    const float* __restrict__ Wf, const float* __restrict__ bf,
    float* __restrict__ out)
{
    __shared__ float sh[113];
    int r = blockIdx.x, t = threadIdx.x;
    if (t < 113) {
        float v;
        if (t < 68) {
            int f = r * 68 + t;                       // h1.reshape(250,68) flat
            v = ws_f[OFF_G1 + f] + b1[f % 200];
        } else {
            int f = r * 45 + (t - 68);                // h2.reshape(250,45) flat
            v = ws_f[OFF_G2 + f] + b2[f & 1];
        }
        sh[t] = fmaxf(v, 0.f);
    }
    __syncthreads();
    if (t < 5) {
        float s = bf[t];
        #pragma unroll 1
        for (int k = 0; k < 113; ++k)
            s = fmaf(sh[k], Wf[k * 5 + t], s);
        out[r * 5 + t] = s;
    }
}

extern "C" void kernel_launch(void* const* d_in, const int* in_sizes, int n_in,
                              void* d_out, int out_size, void* d_ws, size_t ws_size,
                              hipStream_t stream)
{
    const float* x1 = (const float*)d_in[0];
    const float* x2 = (const float*)d_in[1];
    const float* W1 = (const float*)d_in[2];
    const float* b1 = (const float*)d_in[3];
    const float* W2 = (const float*)d_in[4];
    const float* b2 = (const float*)d_in[5];
    const float* Wf = (const float*)d_in[6];
    const float* bf = (const float*)d_in[7];
    const int*   ei1 = (const int*)d_in[8];
    const int*   ei2 = (const int*)d_in[9];
    float* ws_f = (float*)d_ws;
    float* out  = (float*)d_out;

    k1_hist_gemm_zero<<<K1_GRID, 256, 0, stream>>>(x1, x2, W1, W2, ei2, ws_f);
    k2_agg<<<K2_GRID, 256, 0, stream>>>(ei1, ei2, ws_f);
    k3_head<<<250, 128, 0, stream>>>(ws_f, b1, b2, Wf, bf, out);
}

// Round 9
// 58.078 us; speedup vs baseline: 3.0392x; 1.3881x over previous
//
#include <hip/hip_runtime.h>

// Problem constants
constexpr int cN1 = 85,  cF1 = 256, cO1 = 200, cE1 = 1360;
constexpr int cN2 = 5625, cF2 = 128, cE2 = 180000;

// deg2: NPART edge-sliced partial LDS histograms (plain-stored, no atomics)
constexpr int NPART = 8;
constexpr int PBINS = 5632;              // >= cN2, 64-aligned
constexpr int EPP   = cE2 / NPART;       // 22500

// g2 aggregation: NS edge-slices x NR node-ranges, partial sums in LDS,
// plain-stored; reduced in the head kernel. NO global f32 atomics anywhere.
constexpr int NS  = 16;                  // edge slices
constexpr int ESL = cE2 / NS;            // 11250 edges per slice
constexpr int NR  = 16;                  // node ranges
constexpr int RNG = PBINS / NR;          // 352 nodes per range

// Workspace layout (4-byte words) — nothing needs pre-zeroing:
constexpr int OFF_PART = 0;                          // 8*5632 i32 deg partials
constexpr int OFF_P2   = NPART * PBINS;              // 45056: NS*PBINS*2 f32 g2 partials
constexpr int OFF_G1   = OFF_P2 + NS * PBINS * 2;    // 225280: 17000 f32
constexpr int OFF_H1   = OFF_G1 + cN1 * cO1;         // 242280: 17000 f32 (x1@W1)
constexpr int OFF_H2   = OFF_H1 + cN1 * cO1;         // 259280: 11250 f32 (x2@W2), even

// ---------------- K1: deg partial hists + GEMMs (role-split grid) ---------------
// roles: [0,8) hist | [8,93) GEMM1 | [93,797) GEMM2
constexpr int G1_B    = cN1;                  // 85
constexpr int G2_B    = (cN2 + 7) / 8;        // 704
constexpr int K1_GRID = NPART + G1_B + G2_B;  // 797

__global__ __launch_bounds__(256) void k1_hist_gemm(
    const float* __restrict__ x1, const float* __restrict__ x2,
    const float* __restrict__ W1, const float* __restrict__ W2,
    const int* __restrict__ ei2, float* __restrict__ ws_f)
{
    int* ws_i = reinterpret_cast<int*>(ws_f);
    int b = blockIdx.x, t = threadIdx.x;

    if (b < NPART) {
        // Partial histogram over edge slice [b*EPP, (b+1)*EPP)
        __shared__ int s_h[PBINS];
        for (int i = t; i < PBINS; i += 256) s_h[i] = 0;
        __syncthreads();
        const int* dstp = ei2 + cE2 + b * EPP;
        for (int i = t; i < EPP; i += 256)
            atomicAdd(&s_h[dstp[i]], 1);              // LDS atomic only
        __syncthreads();
        for (int i = t; i < PBINS; i += 256)
            ws_i[OFF_PART + b * PBINS + i] = s_h[i];  // plain store
        return;
    }
    b -= NPART;

    if (b < G1_B) {
        // GEMM1: h1[b][t] = sum_k x1[b][k] * W1[k][t]  (t < 200)
        if (t < cO1) {
            const float* xr = x1 + b * cF1;           // uniform across block
            float s = 0.f;
            #pragma unroll 8
            for (int k = 0; k < cF1; ++k)
                s = fmaf(xr[k], W1[k * cO1 + t], s);  // coalesced across t
            ws_f[OFF_H1 + b * cO1 + t] = s;
        }
        return;
    }
    b -= G1_B;

    // GEMM2: 32-lane group per row; W2 (1 KB) cache-resident.
    int row = b * 8 + (t >> 5), l = t & 31;
    if (row < cN2) {
        float4 xv = reinterpret_cast<const float4*>(x2 + row * cF2)[l];
        int kb = l * 4;
        float p0 = xv.x * W2[(kb + 0) * 2 + 0] + xv.y * W2[(kb + 1) * 2 + 0]
                 + xv.z * W2[(kb + 2) * 2 + 0] + xv.w * W2[(kb + 3) * 2 + 0];
        float p1 = xv.x * W2[(kb + 0) * 2 + 1] + xv.y * W2[(kb + 1) * 2 + 1]
                 + xv.z * W2[(kb + 2) * 2 + 1] + xv.w * W2[(kb + 3) * 2 + 1];
        #pragma unroll
        for (int m = 16; m >= 1; m >>= 1) {
            p0 += __shfl_xor(p0, m);
            p1 += __shfl_xor(p1, m);
        }
        if (l == 0) {
            ws_f[OFF_H2 + row * 2 + 0] = p0;
            ws_f[OFF_H2 + row * 2 + 1] = p1;
        }
    }
}

__device__ __forceinline__ int deg2_of(const int* ws_i, int n)
{
    int d = 0;
    #pragma unroll
    for (int p = 0; p < NPART; ++p) d += ws_i[OFF_PART + p * PBINS + n];
    return d;
}

// ---------------- K2: g1 gather + g2 sliced gather (plain stores only) ----------
// roles: [0,85) g1 | [85, 85+NS*NR) g2 partial gather
constexpr int K2_GRID = cN1 + NS * NR;   // 341

__global__ __launch_bounds__(256) void k2_agg(
    const int* __restrict__ ei1, const int* __restrict__ ei2,
    float* __restrict__ ws_f)
{
    const int* ws_i = reinterpret_cast<const int*>(ws_f);
    int b = blockIdx.x, t = threadIdx.x;

    if (b < cN1) {
        // graph1: self-contained gather (deg1 in LDS; no global atomics)
        __shared__ int   s_src[cE1];
        __shared__ int   s_dst[cE1];
        __shared__ int   s_deg[cN1];
        __shared__ float s_acc[cO1];
        for (int i = t; i < cE1; i += 256) { s_src[i] = ei1[i]; s_dst[i] = ei1[cE1 + i]; }
        if (t < cN1) s_deg[t] = 0;
        for (int i = t; i < cO1; i += 256) s_acc[i] = 0.f;
        __syncthreads();
        for (int i = t; i < cE1; i += 256) atomicAdd(&s_deg[s_dst[i]], 1);
        __syncthreads();
        int w = t >> 6, lane = t & 63;
        int e0 = w * (cE1 / 4), e1 = e0 + (cE1 / 4);       // 340 edges / wave
        for (int e = e0; e < e1; ++e) {
            if (s_dst[e] == b) {
                int src = s_src[e];
                float dsv = rsqrtf((float)(s_deg[src] + 1));
                const float* hrow = ws_f + OFF_H1 + src * cO1;
                for (int f = lane; f < cO1; f += 64)
                    atomicAdd(&s_acc[f], hrow[f] * dsv);   // LDS atomic, sparse
            }
        }
        __syncthreads();
        float dn = rsqrtf((float)(s_deg[b] + 1));
        for (int i = t; i < cO1; i += 256)
            ws_f[OFF_G1 + b * cO1 + i] =
                dn * (s_acc[i] + dn * ws_f[OFF_H1 + b * cO1 + i]);
        return;
    }
    b -= cN1;

    // graph2 partial gather: slice s of edges, node range [lo, lo+RNG)
    {
        int s = b >> 4, r = b & 15;
        int lo = r * RNG;
        __shared__ float s_acc2[RNG * 2];                  // 2816 B
        for (int i = t; i < RNG * 2; i += 256) s_acc2[i] = 0.f;
        __syncthreads();
        int e0 = s * ESL;
        for (int i = t; i < ESL; i += 256) {
            int e = e0 + i;
            int d = ei2[cE2 + e];                          // coalesced
            unsigned rel = (unsigned)(d - lo);
            if (rel < (unsigned)RNG) {
                int src = ei2[e];
                float dv = rsqrtf((float)(deg2_of(ws_i, src) + 1));
                float2 h = reinterpret_cast<const float2*>(ws_f + OFF_H2)[src];
                atomicAdd(&s_acc2[rel * 2 + 0], h.x * dv); // LDS atomic
                atomicAdd(&s_acc2[rel * 2 + 1], h.y * dv);
            }
        }
        __syncthreads();
        // plain-store partials: part2[s][lo+j][c]
        float* dst = ws_f + OFF_P2 + (s * PBINS + lo) * 2;
        for (int i = t; i < RNG * 2; i += 256) dst[i] = s_acc2[i];
    }
}

// ---------------- K3: reduce partials + bias + concat + relu + final linear -----
__global__ __launch_bounds__(128) void k3_head(
    const float* __restrict__ ws_f,
    const float* __restrict__ b1, const float* __restrict__ b2,
    const float* __restrict__ Wf, const float* __restrict__ bf,
    float* __restrict__ out)
{
    const int* ws_i = reinterpret_cast<const int*>(ws_f);
    __shared__ float sh[113];
    int r = blockIdx.x, t = threadIdx.x;
    if (t < 113) {
        float v;
        if (t < 68) {
            int f = r * 68 + t;                       // h1.reshape(250,68) flat
            v = ws_f[OFF_G1 + f] + b1[f % 200];
        } else {
            int f = r * 45 + (t - 68);                // h2.reshape(250,45) flat
            int n = f >> 1, c = f & 1;
            float sum = 0.f;
            #pragma unroll
            for (int s = 0; s < NS; ++s)
                sum += ws_f[OFF_P2 + (s * PBINS + n) * 2 + c];
            float dv = rsqrtf((float)(deg2_of(ws_i, n) + 1));
            float hc = ws_f[OFF_H2 + n * 2 + c];
            v = dv * sum + dv * dv * hc + b2[c];      // neighbor part + self loop
        }
        sh[t] = fmaxf(v, 0.f);
    }
    __syncthreads();
    if (t < 5) {
        float s = bf[t];
        #pragma unroll 1
        for (int k = 0; k < 113; ++k)
            s = fmaf(sh[k], Wf[k * 5 + t], s);
        out[r * 5 + t] = s;
    }
}

extern "C" void kernel_launch(void* const* d_in, const int* in_sizes, int n_in,
                              void* d_out, int out_size, void* d_ws, size_t ws_size,
                              hipStream_t stream)
{
    const float* x1 = (const float*)d_in[0];
    const float* x2 = (const float*)d_in[1];
    const float* W1 = (const float*)d_in[2];
    const float* b1 = (const float*)d_in[3];
    const float* W2 = (const float*)d_in[4];
    const float* b2 = (const float*)d_in[5];
    const float* Wf = (const float*)d_in[6];
    const float* bf = (const float*)d_in[7];
    const int*   ei1 = (const int*)d_in[8];
    const int*   ei2 = (const int*)d_in[9];
    float* ws_f = (float*)d_ws;
    float* out  = (float*)d_out;

    k1_hist_gemm<<<K1_GRID, 256, 0, stream>>>(x1, x2, W1, W2, ei2, ws_f);
    k2_agg<<<K2_GRID, 256, 0, stream>>>(ei1, ei2, ws_f);
    k3_head<<<250, 128, 0, stream>>>(ws_f, b1, b2, Wf, bf, out);
}